// Round 9
// baseline (719.284 us; speedup 1.0000x reference)
//
#include <hip/hip_runtime.h>
#include <hip/hip_bf16.h>
#include <math.h>

// B=4, S=2048, C=1024, H=16, HS=64
// Inputs (fp32, dict order): x[4,2048,1024], Wq/Wk/Wv[16,1024,64],
//                            Wp[1024,1024], bp[1024]
// Output: FP32 [4,2048,1024]
// R9: flash = BARRIER-FREE. K/V MFMA B-fragments loaded directly from global
// (both are contiguous 16B runs in the chosen layouts); LDS only for the
// wave-private P C->A transpose. Waves fully independent -> pure TLP hiding.

typedef __bf16 bf16_t;
typedef __bf16 bf16x8 __attribute__((ext_vector_type(8)));
typedef float f32x4 __attribute__((ext_vector_type(4)));

#define S_LEN 2048
#define C_DIM 1024
#define NHEAD 16
#define HS_DIM 64
#define MROWS 8192   // B*S

__device__ __forceinline__ void cvt8(bf16_t* dst, const float* __restrict__ src) {
  const float4 a = *(const float4*)src;
  const float4 b = *(const float4*)(src + 4);
  bf16x8 v;
  v[0] = (bf16_t)a.x; v[1] = (bf16_t)a.y; v[2] = (bf16_t)a.z; v[3] = (bf16_t)a.w;
  v[4] = (bf16_t)b.x; v[5] = (bf16_t)b.y; v[6] = (bf16_t)b.z; v[7] = (bf16_t)b.w;
  *(bf16x8*)dst = v;
}

// ---------------------------------------------------------------------------
// Pack Wq,Wk,Wv (fp32 [16,1024,64]) -> bf16 WT[3072,1024].
// ---------------------------------------------------------------------------
__global__ __launch_bounds__(256) void pack_w_kernel(
    const float* __restrict__ Wq, const float* __restrict__ Wk,
    const float* __restrict__ Wv, bf16_t* __restrict__ WT) {
  __shared__ __align__(16) float tile[64][68];
  const int wsel = blockIdx.z;
  const int h = blockIdx.y;
  const int c0 = blockIdx.x * 64;
  const float* W = (wsel == 0 ? Wq : (wsel == 1 ? Wk : Wv)) + (size_t)h * (C_DIM * HS_DIM);
  const int tr = threadIdx.x >> 2;
  const int tc = (threadIdx.x & 3) << 4;
  #pragma unroll
  for (int j = 0; j < 16; j += 4)
    *(float4*)&tile[tr][tc + j] = *(const float4*)(W + (size_t)(c0 + tr) * HS_DIM + tc + j);
  __syncthreads();
  const int d = threadIdx.x >> 2;
  const int cb = (threadIdx.x & 3) << 4;
  bf16_t* dst = WT + ((size_t)(wsel * 1024 + h * 64 + d)) * C_DIM + c0 + cb;
  #pragma unroll
  for (int i = 0; i < 16; ++i) dst[i] = (bf16_t)tile[cb + i][d];
}

// ---------------------------------------------------------------------------
// QKV projection: x[8192,1024](fp32) x WT[3072,1024](bf16)^T. 128x128x64.
// ---------------------------------------------------------------------------
__global__ __launch_bounds__(256) void gemm_qkv128(
    const float* __restrict__ x, const bf16_t* __restrict__ WT,
    bf16_t* __restrict__ Q, bf16_t* __restrict__ K, bf16_t* __restrict__ VT) {
  __shared__ __align__(16) bf16_t As[128][72];
  __shared__ __align__(16) bf16_t Bs[128][72];
  const int m0 = blockIdx.x * 128;
  const int n0 = blockIdx.y * 128;
  const int tid = threadIdx.x;
  const int wave = tid >> 6, lane = tid & 63, quad = lane >> 4, lid = lane & 15;
  const int ww = wave >> 1, wc = wave & 1;
  const int ar = tid >> 1, ac = (tid & 1) << 5;

  f32x4 acc[4][4] = {};

  for (int k0 = 0; k0 < C_DIM; k0 += 64) {
    #pragma unroll
    for (int j = 0; j < 32; j += 8)
      cvt8(&As[ar][ac + j], x + (size_t)(m0 + ar) * C_DIM + k0 + ac + j);
    #pragma unroll
    for (int j = 0; j < 32; j += 8)
      *(uint4*)&Bs[ar][ac + j] = *(const uint4*)(WT + (size_t)(n0 + ar) * C_DIM + k0 + ac + j);
    __syncthreads();
    #pragma unroll
    for (int c = 0; c < 2; ++c) {
      bf16x8 af[4], bfr[4];
      #pragma unroll
      for (int mt = 0; mt < 4; ++mt)
        af[mt] = *(const bf16x8*)&As[ww * 64 + mt * 16 + lid][c * 32 + quad * 8];
      #pragma unroll
      for (int nt = 0; nt < 4; ++nt)
        bfr[nt] = *(const bf16x8*)&Bs[wc * 64 + nt * 16 + lid][c * 32 + quad * 8];
      #pragma unroll
      for (int mt = 0; mt < 4; ++mt)
        #pragma unroll
        for (int nt = 0; nt < 4; ++nt)
          acc[mt][nt] = __builtin_amdgcn_mfma_f32_16x16x32_bf16(af[mt], bfr[nt], acc[mt][nt], 0, 0, 0);
    }
    __syncthreads();
  }

  #pragma unroll
  for (int mt = 0; mt < 4; ++mt) {
    #pragma unroll
    for (int nt = 0; nt < 4; ++nt) {
      #pragma unroll
      for (int r = 0; r < 4; ++r) {
        const int row = m0 + ww * 64 + mt * 16 + quad * 4 + r;
        const int col = n0 + wc * 64 + nt * 16 + lid;
        const int wsel = col >> 10, h = (col >> 6) & 15, d = col & 63;
        const bf16_t bv = (bf16_t)acc[mt][nt][r];
        if (wsel == 0) {
          Q[(size_t)row * C_DIM + h * HS_DIM + d] = bv;
        } else if (wsel == 1) {
          K[(size_t)row * C_DIM + h * HS_DIM + d] = bv;
        } else {
          const int b = row >> 11, s = row & 2047;
          VT[((size_t)(b * NHEAD + h) * HS_DIM + d) * S_LEN + s] = bv;
        }
      }
    }
  }
}

// ---------------------------------------------------------------------------
// Flash attention (causal), barrier-free. grid (32 desc-LPT, 64 bh);
// block = 4 independent waves, each owning a 16-row Q strip.
// K-frag: Bt[n=t][k=d] = K[rb+t][h*64+d]   (contig 8 bf16 along d)
// V-frag: Bt[n=d][k=t] = VT[bh*64+d][t]    (contig 8 bf16 along t)
// P: C->A layout via wave-private LDS (in-wave DS ordering; r2==r5 verified).
// ---------------------------------------------------------------------------
__global__ __launch_bounds__(256) void flash_attn_kernel(
    const bf16_t* __restrict__ Q,   // [8192,1024]
    const bf16_t* __restrict__ Kb,  // [8192,1024]
    const bf16_t* __restrict__ VT,  // [64,64,2048]
    bf16_t* __restrict__ O) {       // [8192,1024]
  __shared__ __align__(16) bf16_t Ps[4][16][72];
  const int s0 = (31 - blockIdx.x) * 64;     // LPT: long blocks first
  const int bh = blockIdx.y;
  const int b = bh >> 4, h = bh & 15;
  const int rb = b * S_LEN;
  const int tid = threadIdx.x;
  const int wave = tid >> 6, lane = tid & 63, quad = lane >> 4, lid = lane & 15;
  const float scale = 0.125f;

  // Q fragments (A-layout): row = s0+wave*16+lid, k = c*32+quad*8+j
  const size_t qbase = (size_t)(rb + s0 + wave * 16 + lid) * C_DIM + h * HS_DIM;
  bf16x8 qfrag[2];
  qfrag[0] = *(const bf16x8*)(Q + qbase + quad * 8);
  qfrag[1] = *(const bf16x8*)(Q + qbase + 32 + quad * 8);

  // Per-lane global bases for direct B-fragment loads.
  const bf16_t* kfb = Kb + (size_t)(rb + lid) * C_DIM + h * HS_DIM + quad * 8;  // +(t0+nt*16)*C_DIM + c*32
  const bf16_t* vfb = VT + ((size_t)bh * HS_DIM + lid) * S_LEN + quad * 8;      // +(dt*16)*S_LEN + t0 + c*32

  f32x4 oacc[4] = {};
  float m_i[4], l_i[4];
  #pragma unroll
  for (int r = 0; r < 4; ++r) { m_i[r] = -INFINITY; l_i[r] = 0.f; }

  for (int t0 = 0; t0 <= s0; t0 += 64) {
    // ---- S = Q K^T : K fragments straight from global ----
    f32x4 sacc[4] = {};
    #pragma unroll
    for (int c = 0; c < 2; ++c) {
      bf16x8 kf[4];
      #pragma unroll
      for (int nt = 0; nt < 4; ++nt)
        kf[nt] = *(const bf16x8*)(kfb + (size_t)(t0 + nt * 16) * C_DIM + c * 32);
      #pragma unroll
      for (int nt = 0; nt < 4; ++nt)
        sacc[nt] = __builtin_amdgcn_mfma_f32_16x16x32_bf16(qfrag[c], kf[nt], sacc[nt], 0, 0, 0);
    }
    const bool diag = (t0 == s0);
    #pragma unroll
    for (int nt = 0; nt < 4; ++nt) {
      #pragma unroll
      for (int r = 0; r < 4; ++r) {
        float v = sacc[nt][r] * scale;
        if (diag) {
          const int srow = wave * 16 + quad * 4 + r;
          const int tcol = nt * 16 + lid;
          if (tcol > srow) v = -INFINITY;
        }
        sacc[nt][r] = v;
      }
    }
    // ---- online softmax (row max over 64 cols: 4 tiles + lid butterfly) ----
    float alpha[4], rsum[4];
    #pragma unroll
    for (int r = 0; r < 4; ++r) {
      float v = fmaxf(fmaxf(sacc[0][r], sacc[1][r]), fmaxf(sacc[2][r], sacc[3][r]));
      v = fmaxf(v, __shfl_xor(v, 1));
      v = fmaxf(v, __shfl_xor(v, 2));
      v = fmaxf(v, __shfl_xor(v, 4));
      v = fmaxf(v, __shfl_xor(v, 8));
      const float mnew = fmaxf(m_i[r], v);
      alpha[r] = __expf(m_i[r] - mnew);
      m_i[r] = mnew;
      rsum[r] = 0.f;
    }
    #pragma unroll
    for (int nt = 0; nt < 4; ++nt) {
      #pragma unroll
      for (int r = 0; r < 4; ++r) {
        const float pv = __expf(sacc[nt][r] - m_i[r]);
        rsum[r] += pv;
        Ps[wave][quad * 4 + r][nt * 16 + lid] = (bf16_t)pv;   // wave-private
      }
    }
    #pragma unroll
    for (int r = 0; r < 4; ++r) {
      float v = rsum[r];
      v += __shfl_xor(v, 1);
      v += __shfl_xor(v, 2);
      v += __shfl_xor(v, 4);
      v += __shfl_xor(v, 8);
      l_i[r] = l_i[r] * alpha[r] + v;
    }
    #pragma unroll
    for (int dt = 0; dt < 4; ++dt) {
      #pragma unroll
      for (int r = 0; r < 4; ++r) oacc[dt][r] *= alpha[r];
    }
    // ---- O += P V : V fragments straight from global ----
    #pragma unroll
    for (int c = 0; c < 2; ++c) {
      bf16x8 pfrag = *(const bf16x8*)&Ps[wave][lid][c * 32 + quad * 8];
      bf16x8 vf[4];
      #pragma unroll
      for (int dt = 0; dt < 4; ++dt)
        vf[dt] = *(const bf16x8*)(vfb + (size_t)(dt * 16) * S_LEN + t0 + c * 32);
      #pragma unroll
      for (int dt = 0; dt < 4; ++dt)
        oacc[dt] = __builtin_amdgcn_mfma_f32_16x16x32_bf16(pfrag, vf[dt], oacc[dt], 0, 0, 0);
    }
  }

  #pragma unroll
  for (int dt = 0; dt < 4; ++dt) {
    #pragma unroll
    for (int r = 0; r < 4; ++r) {
      const int row = rb + s0 + wave * 16 + quad * 4 + r;
      const int d = dt * 16 + lid;
      O[(size_t)row * C_DIM + h * HS_DIM + d] = (bf16_t)(oacc[dt][r] / l_i[r]);
    }
  }
}

// ---------------------------------------------------------------------------
// Output projection: out = O @ Wp^T + bp (fp32 stores). 128x128x64 tiles.
// ---------------------------------------------------------------------------
__global__ __launch_bounds__(256) void gemm_out128(
    const bf16_t* __restrict__ A,    // [8192,1024] O
    const float* __restrict__ Wp,    // [1024,1024]
    const float* __restrict__ bias,  // [1024]
    float* __restrict__ out) {       // [8192,1024] fp32
  __shared__ __align__(16) bf16_t As[128][72];
  __shared__ __align__(16) bf16_t Bs[128][72];
  const int m0 = blockIdx.x * 128;
  const int n0 = blockIdx.y * 128;
  const int tid = threadIdx.x;
  const int wave = tid >> 6, lane = tid & 63, quad = lane >> 4, lid = lane & 15;
  const int ww = wave >> 1, wc = wave & 1;
  const int ar = tid >> 1, ac = (tid & 1) << 5;

  f32x4 acc[4][4] = {};

  for (int k0 = 0; k0 < C_DIM; k0 += 64) {
    #pragma unroll
    for (int j = 0; j < 32; j += 8)
      *(uint4*)&As[ar][ac + j] = *(const uint4*)(A + (size_t)(m0 + ar) * C_DIM + k0 + ac + j);
    #pragma unroll
    for (int j = 0; j < 32; j += 8)
      cvt8(&Bs[ar][ac + j], Wp + (size_t)(n0 + ar) * C_DIM + k0 + ac + j);
    __syncthreads();
    #pragma unroll
    for (int c = 0; c < 2; ++c) {
      bf16x8 af[4], bfr[4];
      #pragma unroll
      for (int mt = 0; mt < 4; ++mt)
        af[mt] = *(const bf16x8*)&As[ww * 64 + mt * 16 + lid][c * 32 + quad * 8];
      #pragma unroll
      for (int nt = 0; nt < 4; ++nt)
        bfr[nt] = *(const bf16x8*)&Bs[wc * 64 + nt * 16 + lid][c * 32 + quad * 8];
      #pragma unroll
      for (int mt = 0; mt < 4; ++mt)
        #pragma unroll
        for (int nt = 0; nt < 4; ++nt)
          acc[mt][nt] = __builtin_amdgcn_mfma_f32_16x16x32_bf16(af[mt], bfr[nt], acc[mt][nt], 0, 0, 0);
    }
    __syncthreads();
  }

  #pragma unroll
  for (int mt = 0; mt < 4; ++mt) {
    #pragma unroll
    for (int nt = 0; nt < 4; ++nt) {
      #pragma unroll
      for (int r = 0; r < 4; ++r) {
        const int row = m0 + ww * 64 + mt * 16 + quad * 4 + r;
        const int col = n0 + wc * 64 + nt * 16 + lid;
        out[(size_t)row * C_DIM + col] = acc[mt][nt][r] + bias[col];
      }
    }
  }
}

// ---------------------------------------------------------------------------
extern "C" void kernel_launch(void* const* d_in, const int* in_sizes, int n_in,
                              void* d_out, int out_size, void* d_ws, size_t ws_size,
                              hipStream_t stream) {
  const float *x, *Wq, *Wk, *Wv, *Wp, *bp;
  if (in_sizes[0] == MROWS * C_DIM) {            // dict order (confirmed)
    x  = (const float*)d_in[0];
    Wq = (const float*)d_in[1];
    Wk = (const float*)d_in[2];
    Wv = (const float*)d_in[3];
    Wp = (const float*)d_in[4];
    bp = (const float*)d_in[5];
  } else {                                        // key-sorted hedge
    Wk = (const float*)d_in[0];
    Wp = (const float*)d_in[1];
    Wq = (const float*)d_in[2];
    Wv = (const float*)d_in[3];
    bp = (const float*)d_in[4];
    x  = (const float*)d_in[5];
  }
  float* out = (float*)d_out;

  // ws = 64 MB: [Ob 16MB (WT aliases; dead before flash)][Qb][Kb][VTb]
  const size_t NB = (size_t)MROWS * C_DIM;
  bf16_t* ws  = (bf16_t*)d_ws;
  bf16_t* Ob  = ws;
  bf16_t* WT  = ws;            // aliases Ob, dead after QKV GEMM
  bf16_t* Qb  = ws + NB;
  bf16_t* Kb  = Qb + NB;
  bf16_t* VTb = Kb + NB;

  pack_w_kernel<<<dim3(16, 16, 3), 256, 0, stream>>>(Wq, Wk, Wv, WT);
  gemm_qkv128<<<dim3(64, 24), 256, 0, stream>>>(x, WT, Qb, Kb, VTb);
  flash_attn_kernel<<<dim3(32, 64), 256, 0, stream>>>(Qb, Kb, VTb, Ob);
  gemm_out128<<<dim3(64, 8), 256, 0, stream>>>(Ob, Wp, bp, out);
}